// Round 7
// baseline (258.017 us; speedup 1.0000x reference)
//
#include <hip/hip_runtime.h>
#include <stdint.h>

#define B_    4
#define S_    2048
#define DM    1024
#define NH    16
#define DH    64
#define BH    (B_ * NH)    // 64
#define MROWS (B_ * S_)    // 8192
#define LOG2E 1.4426950408889634f

typedef __attribute__((ext_vector_type(8))) short short8;
typedef __attribute__((ext_vector_type(4))) float f32x4;
typedef __attribute__((ext_vector_type(16))) float f32x16;
typedef __attribute__((ext_vector_type(4))) unsigned int u32x4;

__device__ __forceinline__ unsigned short f2bf(float f) {
  unsigned int u = __float_as_uint(f);
  u = (u + 0x7FFFu + ((u >> 16) & 1u)) >> 16;
  return (unsigned short)u;
}
// round-half-up pack (PROVEN in R4)
__device__ __forceinline__ unsigned int pack_bf16(float lo, float hi) {
  unsigned int a = (__float_as_uint(lo) + 0x8000u) >> 16;
  unsigned int b = (__float_as_uint(hi) + 0x8000u) & 0xFFFF0000u;
  return a | b;
}

__device__ __forceinline__ void gll16(const void* g, const void* l) {
  __builtin_amdgcn_global_load_lds(
      (__attribute__((address_space(1))) void*)(unsigned long long)g,
      (__attribute__((address_space(3))) void*)(unsigned int)(unsigned long long)l,
      16, 0, 0);
}

// ---------------------------------------------------------------- prep
// z in [0,3]: W[z] fp32 [k][n] -> W^T bf16 [n][k].  z in [4,7]: x -> bf16.
__global__ __launch_bounds__(256) void prep_kernel(
    const float* __restrict__ x,
    const float* __restrict__ Wq, const float* __restrict__ Wk,
    const float* __restrict__ Wv, const float* __restrict__ Wo,
    unsigned short* __restrict__ xb,
    unsigned short* __restrict__ wt_qkv, unsigned short* __restrict__ wt_o) {
  __shared__ float t[32][33];
  const int z = blockIdx.z;
  if (z >= 4) {
    size_t lb = (size_t)(z - 4) * 1024 + blockIdx.y * 32 + blockIdx.x;
    size_t i = (lb * 256 + threadIdx.x) * 8;
    float4 a = *(const float4*)(x + i);
    float4 b = *(const float4*)(x + i + 4);
    short8 o;
    o[0] = (short)f2bf(a.x); o[1] = (short)f2bf(a.y);
    o[2] = (short)f2bf(a.z); o[3] = (short)f2bf(a.w);
    o[4] = (short)f2bf(b.x); o[5] = (short)f2bf(b.y);
    o[6] = (short)f2bf(b.z); o[7] = (short)f2bf(b.w);
    *(short8*)(xb + i) = o;
    return;
  }
  const float* W = z == 0 ? Wq : z == 1 ? Wk : z == 2 ? Wv : Wo;
  unsigned short* dst = z < 3 ? wt_qkv + (size_t)z * DM * DM : wt_o;
  const int nb = blockIdx.x * 32, kb = blockIdx.y * 32;
  const int tx = threadIdx.x & 31, ty = threadIdx.x >> 5;
#pragma unroll
  for (int p = 0; p < 4; ++p) {
    int r = ty + p * 8;
    t[r][tx] = W[(size_t)(kb + r) * DM + nb + tx];
  }
  __syncthreads();
#pragma unroll
  for (int p = 0; p < 4; ++p) {
    int r = ty + p * 8;
    dst[(size_t)(nb + r) * DM + kb + tx] = f2bf(t[tx][r]);
  }
}

// ---------------------------------------------------------------- GEMM core (128x128, 256 thr)
// 32x32x16 MFMA; layouts HW-verified. Used by gemm_out.
__device__ __forceinline__ void gemm_core(const unsigned short* __restrict__ A,
                                          const unsigned short* __restrict__ Bt,
                                          int m0, int n0,
                                          unsigned short* As, unsigned short* Bs,
                                          f32x16 (&acc)[2][2]) {
  const int tid = threadIdx.x;
  const int lane = tid & 63, wave = tid >> 6;
  const int l31 = lane & 31, half = lane >> 5;
  const int wm = (wave >> 1) * 64, wn = (wave & 1) * 64;

  for (int kk = 0; kk < DM; kk += 64) {
#pragma unroll
    for (int p = 0; p < 4; ++p) {
      int idx = p * 256 + tid;
      int row = idx >> 3, ch = idx & 7;
      int sc = (ch ^ (row & 7)) << 3;
      gll16(A  + (size_t)(m0 + row) * DM + kk + sc, As + idx * 8);
      gll16(Bt + (size_t)(n0 + row) * DM + kk + sc, Bs + idx * 8);
    }
    __syncthreads();
#pragma unroll
    for (int ks = 0; ks < 4; ++ks) {   // 4 k-steps of 16
      short8 af[2], bf[2];
#pragma unroll
      for (int mi = 0; mi < 2; ++mi) {
        int row = wm + mi * 32 + l31;
        af[mi] = *(const short8*)&As[row * 64 + (((ks * 2 + half) ^ (l31 & 7)) << 3)];
      }
#pragma unroll
      for (int nj = 0; nj < 2; ++nj) {
        int row = wn + nj * 32 + l31;
        bf[nj] = *(const short8*)&Bs[row * 64 + (((ks * 2 + half) ^ (l31 & 7)) << 3)];
      }
#pragma unroll
      for (int mi = 0; mi < 2; ++mi)
#pragma unroll
        for (int nj = 0; nj < 2; ++nj)
          acc[mi][nj] = __builtin_amdgcn_mfma_f32_32x32x16_bf16(af[mi], bf[nj], acc[mi][nj], 0, 0, 0);
    }
    __syncthreads();
  }
}

// ---------------------------------------------------------------- GEMM core (256x256, 512 thr, 8-phase)
// T2(swizzle)+T3/T4(phased, counted vmcnt)+T5(setprio) port of the 256^2
// template, built from THIS session's proven atoms:
//  - per-row XOR chunk swizzle (involution; same as gemm_core) on both
//    stage source and ds_read (rule #21).
//  - 32x32x16 fragment reads identical to gemm_core.
//  - raw s_barrier + counted vmcnt: ONE vmcnt(2) per K-tile, issued AFTER
//    the first half-tile stage of tile t+1 so 2 loads stay in flight
//    (never drain to 0 mid-loop). sched_barrier(0) after every s_barrier
//    (rule #18: stops loads/stages hoisting across the raw barrier).
//  - FP accumulation order identical to gemm_core -> numerics unchanged.
// LDS 128 KiB (2buf x (A,B) x 256x64 bf16) -> 1 block/CU; ILP replaces TLP.
__device__ __forceinline__ void stage_half(const unsigned short* __restrict__ G,
                                           size_t grow0, int kk,
                                           unsigned short* lds, int tid) {
  // grow0 % 128 == 0, so (grow0+rl)&7 == rl&7.
#pragma unroll
  for (int ls = 0; ls < 2; ++ls) {
    int idx = ls * 512 + tid;          // 0..1023 chunk slot (16B each)
    int rl = idx >> 3, ch = idx & 7;
    int sc = (ch ^ (rl & 7)) << 3;     // pre-swizzled global source
    gll16(G + (grow0 + rl) * DM + kk + sc, lds + idx * 8);
  }
}

#define MFMA_BF16_32(a, b, c) __builtin_amdgcn_mfma_f32_32x32x16_bf16(a, b, c, 0, 0, 0)
#define SBAR() do { __builtin_amdgcn_s_barrier(); __builtin_amdgcn_sched_barrier(0); } while (0)

__device__ __forceinline__ void gemm256_core(const unsigned short* __restrict__ A,
                                             const unsigned short* __restrict__ Bt,
                                             int m0, int n0,
                                             unsigned short* As, unsigned short* Bs,
                                             f32x16 (&acc)[4][2]) {
  const int tid = threadIdx.x;
  const int lane = tid & 63, wave = tid >> 6;
  const int l31 = lane & 31, half = lane >> 5;
  const int wm = (wave >> 2) * 128, wn = (wave & 3) * 64;
  const int NT = DM / 64;  // 16

  // prologue: tile 0 -> buf 0 (8 loads/thread); no wait here — phase 0 of
  // t=0 issues 2 more then vmcnt(2) => exactly tile 0 drained.
  stage_half(A,  (size_t)m0,        0, As, tid);
  stage_half(A,  (size_t)m0 + 128,  0, As + 8192, tid);
  stage_half(Bt, (size_t)n0,        0, Bs, tid);
  stage_half(Bt, (size_t)n0 + 128,  0, Bs + 8192, tid);

  int p = 0;
  for (int t = 0; t < NT; ++t, p ^= 1) {
    unsigned short* Ap = As + p * 16384;
    unsigned short* Bp = Bs + p * 16384;
    unsigned short* An = As + (p ^ 1) * 16384;
    unsigned short* Bn = Bs + (p ^ 1) * 16384;
    const int kk1 = (t + 1) * 64;
    const bool pre = (t + 1 < NT);

    short8 af[2][4], bf[4];

    // -- phase 0: stage A-h0(t+1); wait tile t (counted); MFMA (m0,m1)xn0
    if (pre) {
      stage_half(A, (size_t)m0, kk1, An, tid);
      asm volatile("s_waitcnt vmcnt(2)" ::: "memory");
    } else {
      asm volatile("s_waitcnt vmcnt(0)" ::: "memory");
    }
    SBAR();  // all waves: tile t resident
#pragma unroll
    for (int mi = 0; mi < 2; ++mi) {
      int row = wm + mi * 32 + l31;
#pragma unroll
      for (int ks = 0; ks < 4; ++ks)
        af[mi][ks] = *(const short8*)&Ap[row * 64 + (((ks * 2 + half) ^ (l31 & 7)) << 3)];
    }
    {
      int row = wn + l31;
#pragma unroll
      for (int ks = 0; ks < 4; ++ks)
        bf[ks] = *(const short8*)&Bp[row * 64 + (((ks * 2 + half) ^ (l31 & 7)) << 3)];
    }
    __builtin_amdgcn_s_setprio(1);
#pragma unroll
    for (int ks = 0; ks < 4; ++ks) {
      acc[0][0] = MFMA_BF16_32(af[0][ks], bf[ks], acc[0][0]);
      acc[1][0] = MFMA_BF16_32(af[1][ks], bf[ks], acc[1][0]);
    }
    __builtin_amdgcn_s_setprio(0);
    SBAR();

    // -- phase 1: stage A-h1(t+1); MFMA (m0,m1)xn1 (af reused)
    if (pre) stage_half(A, (size_t)m0 + 128, kk1, An + 8192, tid);
    {
      int row = wn + 32 + l31;
#pragma unroll
      for (int ks = 0; ks < 4; ++ks)
        bf[ks] = *(const short8*)&Bp[row * 64 + (((ks * 2 + half) ^ (l31 & 7)) << 3)];
    }
    __builtin_amdgcn_s_setprio(1);
#pragma unroll
    for (int ks = 0; ks < 4; ++ks) {
      acc[0][1] = MFMA_BF16_32(af[0][ks], bf[ks], acc[0][1]);
      acc[1][1] = MFMA_BF16_32(af[1][ks], bf[ks], acc[1][1]);
    }
    __builtin_amdgcn_s_setprio(0);
    SBAR();

    // -- phase 2: stage B-h0(t+1); MFMA (m2,m3)xn1 (bf reused)
    if (pre) stage_half(Bt, (size_t)n0, kk1, Bn, tid);
#pragma unroll
    for (int mi = 0; mi < 2; ++mi) {
      int row = wm + 64 + mi * 32 + l31;
#pragma unroll
      for (int ks = 0; ks < 4; ++ks)
        af[mi][ks] = *(const short8*)&Ap[row * 64 + (((ks * 2 + half) ^ (l31 & 7)) << 3)];
    }
    __builtin_amdgcn_s_setprio(1);
#pragma unroll
    for (int ks = 0; ks < 4; ++ks) {
      acc[2][1] = MFMA_BF16_32(af[0][ks], bf[ks], acc[2][1]);
      acc[3][1] = MFMA_BF16_32(af[1][ks], bf[ks], acc[3][1]);
    }
    __builtin_amdgcn_s_setprio(0);
    SBAR();

    // -- phase 3: stage B-h1(t+1); MFMA (m2,m3)xn0 (af reused, bf reload n0)
    if (pre) stage_half(Bt, (size_t)n0 + 128, kk1, Bn + 8192, tid);
    {
      int row = wn + l31;
#pragma unroll
      for (int ks = 0; ks < 4; ++ks)
        bf[ks] = *(const short8*)&Bp[row * 64 + (((ks * 2 + half) ^ (l31 & 7)) << 3)];
    }
    __builtin_amdgcn_s_setprio(1);
#pragma unroll
    for (int ks = 0; ks < 4; ++ks) {
      acc[2][0] = MFMA_BF16_32(af[0][ks], bf[ks], acc[2][0]);
      acc[3][0] = MFMA_BF16_32(af[1][ks], bf[ks], acc[3][0]);
    }
    __builtin_amdgcn_s_setprio(0);
    SBAR();  // WAR gate: next iteration's stages may now overwrite buf p
  }
}

// QKV projection, 256^2 8-phase. V written directly in [bh][d][s] layout.
__global__ __launch_bounds__(512, 2) void gemm_qkv_kernel(
    const unsigned short* __restrict__ xb, const unsigned short* __restrict__ wt,
    const float* __restrict__ bq, const float* __restrict__ bk, const float* __restrict__ bv,
    unsigned short* __restrict__ Qb, unsigned short* __restrict__ Kb,
    unsigned short* __restrict__ Vt) {
  __shared__ unsigned short As[2 * 16384];  // 64 KiB
  __shared__ unsigned short Bs[2 * 16384];  // 64 KiB
  f32x16 acc[4][2] = {};
  const int m0 = blockIdx.y * 256, n0 = blockIdx.x * 256;
  gemm256_core(xb, wt, m0, n0, As, Bs, acc);

  const int tid = threadIdx.x, lane = tid & 63, wave = tid >> 6;
  const int l31 = lane & 31, half = lane >> 5;
  const int wm = (wave >> 2) * 128, wn = (wave & 3) * 64;
  const int which = n0 >> 10;               // uniform per block (256 | 1024)
  const int nb = n0 - (which << 10);
  if (which == 2) {
    // V -> Vt[bh][d][s]
#pragma unroll
    for (int nj = 0; nj < 2; ++nj) {
      int n10 = nb + wn + nj * 32 + l31;
      float bsv = bv[n10];
      int h = n10 >> 6, d = n10 & 63;
#pragma unroll
      for (int mi = 0; mi < 4; ++mi) {
#pragma unroll
        for (int reg = 0; reg < 16; ++reg) {
          int m = m0 + wm + mi * 32 + (reg & 3) + 8 * (reg >> 2) + 4 * half;
          int b = m >> 11, s = m & 2047;
          Vt[(((size_t)(b * NH + h)) * DH + d) * S_ + s] = f2bf(acc[mi][nj][reg] + bsv);
        }
      }
    }
    return;
  }
  const float* bias = which == 0 ? bq : bk;
  unsigned short* dst = which == 0 ? Qb : Kb;
  const float scale = (which == 0) ? 0.125f * LOG2E : 1.0f;
#pragma unroll
  for (int nj = 0; nj < 2; ++nj) {
    int n10 = nb + wn + nj * 32 + l31;
    float bsv = bias[n10];
    int h = n10 >> 6, d = n10 & 63;
#pragma unroll
    for (int mi = 0; mi < 4; ++mi) {
#pragma unroll
      for (int reg = 0; reg < 16; ++reg) {
        int m = m0 + wm + mi * 32 + (reg & 3) + 8 * (reg >> 2) + 4 * half;
        int b = m >> 11, s = m & 2047;
        float v = (acc[mi][nj][reg] + bsv) * scale;
        dst[(((size_t)(b * NH + h)) * S_ + s) * DH + d] = f2bf(v);
      }
    }
  }
}

__global__ __launch_bounds__(256) void gemm_out_kernel(
    const unsigned short* __restrict__ ctx, const unsigned short* __restrict__ wto,
    const float* __restrict__ bo, float* __restrict__ out) {
  __shared__ unsigned short As[128 * 64];
  __shared__ unsigned short Bs[128 * 64];
  f32x16 acc[2][2] = {};
  const int m0 = blockIdx.y * 128, n0 = blockIdx.x * 128;
  gemm_core(ctx, wto, m0, n0, As, Bs, acc);

  const int tid = threadIdx.x, lane = tid & 63, wave = tid >> 6;
  const int l31 = lane & 31, half = lane >> 5;
  const int wm = (wave >> 1) * 64, wn = (wave & 1) * 64;
#pragma unroll
  for (int nj = 0; nj < 2; ++nj) {
    int n = n0 + wn + nj * 32 + l31;
    float bsv = bo[n];
#pragma unroll
    for (int mi = 0; mi < 2; ++mi) {
#pragma unroll
      for (int reg = 0; reg < 16; ++reg) {
        int m = m0 + wm + mi * 32 + (reg & 3) + 8 * (reg >> 2) + 4 * half;
        out[(size_t)m * DM + n] = acc[mi][nj][reg] + bsv;
      }
    }
  }
}

// ---------------------------------------------------------------- attention
// R6 PASSING version (32x32x16, shfl_xor+select transform, named regs,
// launch_bounds (256,2)). UNCHANGED this round.

#define TTILE(T, PAE, PAO) do {                                              \
    f32x16 sa;                                                               \
    _Pragma("unroll") for (int r = 0; r < 16; ++r) sa[r] = -8.f;             \
    {                                                                        \
      int row = (T) * 32 + l31;                                              \
      _Pragma("unroll") for (int ks = 0; ks < 4; ++ks) {                     \
        short8 kf = *(const short8*)&Ks[row * 64 +                           \
                      (((ks * 2 + half) ^ (row & 7)) << 3)];                 \
        sa = __builtin_amdgcn_mfma_f32_32x32x16_bf16(kf, qf[ks], sa, 0, 0, 0);\
      }                                                                      \
    }                                                                        \
    if (kt == qt) {                                                          \
      int ql = wave * 32 + l31;                                              \
      _Pragma("unroll") for (int r = 0; r < 16; ++r) {                       \
        int kv = (T) * 32 + (r & 3) + 8 * (r >> 2) + 4 * half;               \
        if (kv > ql) sa[r] = -__builtin_inff();                              \
      }                                                                      \
    }                                                                        \
    float p[16];                                                             \
    _Pragma("unroll") for (int r = 0; r < 16; ++r)                           \
      p[r] = __builtin_amdgcn_exp2f(sa[r]);                                  \
    la0 += p[0] + p[4] + p[8]  + p[12];                                      \
    la1 += p[1] + p[5] + p[9]  + p[13];                                      \
    la2 += p[2] + p[6] + p[10] + p[14];                                      \
    la3 += p[3] + p[7] + p[11] + p[15];                                      \
    {                                                                        \
      unsigned int A0 = pack_bf16(p[0], p[1]), A1 = pack_bf16(p[2], p[3]);   \
      unsigned int B0 = pack_bf16(p[4], p[5]), B1 = pack_bf16(p[6], p[7]);   \
      unsigned int A0x = (unsigned int)__shfl_xor((int)A0, 32);              \
      unsigned int A1x = (unsigned int)__shfl_xor((int)A1, 32);              \
      unsigned int B0x = (unsigned int)__shfl_xor((int)B0, 32);              \
      unsigned int B1x = (unsigned int)__shfl_xor((int)B1, 32);              \
      u32x4 fa;                                                              \
      fa[0] = half ? B0x : A0;                                               \
      fa[1] = half ? B1x : A1;                                               \
      fa[2] = half ? B0  : A0x;                                              \
      fa[3] = half ? B1  : A1x;                                              \
      PAE = __builtin_bit_cast(short8, fa);                                  \
    }                                                                        \
    {                                                                        \
      unsigned int C0 = pack_bf16(p[8], p[9]),   C1 = pack_bf16(p[10], p[11]);\
      unsigned int D0 = pack_bf16(p[12], p[13]), D1 = pack_bf16(p[14], p[15]);\
      unsigned int C0x = (unsigned int)__shfl_xor((int)C0, 32);              \
      unsigned int C1x = (unsigned int)__shfl_xor((int)C1, 32);              \
      unsigned int D0x = (unsigned int)__shfl_xor((int)D0, 32);              \
      unsigned int D1x = (unsigned int)__shfl_xor((int)D1, 32);              \
      u32x4 fb;                                                              \
      fb[0] = half ? D0x : C0;                                               \
      fb[1] = half ? D1x : C1;                                               \
      fb[2] = half ? D0  : C0x;                                              \
      fb[3] = half ? D1  : C1x;                                              \
      PAO = __builtin_bit_cast(short8, fb);                                  \
    }                                                                        \
  } while (0)

#define PVSTEP(S2, PA) do {                                                  \
    int c = (S2) * 2 + half;                                                 \
    {                                                                        \
      int row = l31;                                                         \
      short8 vf = *(const short8*)&Vs[row * 128 +                            \
                    (((c & 8) | ((c ^ row) & 7)) << 3)];                     \
      o0 = __builtin_amdgcn_mfma_f32_32x32x16_bf16(PA, vf, o0, 0, 0, 0);     \
    }                                                                        \
    {                                                                        \
      int row = 32 + l31;                                                    \
      short8 vf = *(const short8*)&Vs[row * 128 +                            \
                    (((c & 8) | ((c ^ row) & 7)) << 3)];                     \
      o1 = __builtin_amdgcn_mfma_f32_32x32x16_bf16(PA, vf, o1, 0, 0, 0);     \
    }                                                                        \
  } while (0)

__global__ __launch_bounds__(256, 2) void attn_kernel(
    const unsigned short* __restrict__ Qb, const unsigned short* __restrict__ Kb,
    const unsigned short* __restrict__ Vt, unsigned short* __restrict__ ctx) {
  __shared__ unsigned short Ks[128 * 64];  // 16 KiB
  __shared__ unsigned short Vs[64 * 128];  // 16 KiB

  const int tid = threadIdx.x, lane = tid & 63, wave = tid >> 6;
  const int l31 = lane & 31, half = lane >> 5;
  const int bh = blockIdx.x;
  const int qt = 15 - blockIdx.y;
  const int b = bh >> 4, h = bh & 15;

  const unsigned short* Qp = Qb + ((size_t)bh * S_ + qt * 128) * DH;
  const unsigned short* Kbase = Kb + (size_t)bh * S_ * DH;
  const unsigned short* Vbase = Vt + (size_t)bh * DH * S_;

  // prologue: K tile 0 -> Ks (async); Q fragments -> registers (direct)
#pragma unroll
  for (int p = 0; p < 4; ++p) {
    int idx = p * 256 + tid;
    int row = idx >> 3, ch = idx & 7;
    int sc = (ch ^ (row & 7)) << 3;
    gll16(Kbase + row * 64 + sc, Ks + idx * 8);
  }
  // Q as B-operand: col=q=wave*32+l31, k=d=ks*16+half*8+j
  short8 qf[4];
#pragma unroll
  for (int ks = 0; ks < 4; ++ks)
    qf[ks] = *(const short8*)(Qp + (wave * 32 + l31) * 64 + ks * 16 + half * 8);
  __syncthreads();  // Ks[0] resident

  f32x16 o0 = {}, o1 = {};  // O: col=d=jd*32+l31, row=q=(r&3)+8*(r>>2)+4*half
  float la0 = 0.f, la1 = 0.f, la2 = 0.f, la3 = 0.f;

  for (int kt = 0; kt <= qt; ++kt) {
    // issue V[kt] NOW; it flies during S + softmax
    const unsigned short* Vp = Vbase + kt * 128;
#pragma unroll
    for (int p = 0; p < 4; ++p) {
      int idx = p * 256 + tid;
      int row = idx >> 4, ch = idx & 15;
      int sc = (ch & 8) | ((ch ^ row) & 7);
      gll16(Vp + (size_t)row * S_ + sc * 8, Vs + idx * 8);
    }

    // S^T = K * Q^T - 8, softmax + pack + cross-half exchange, all in-register
    short8 pa0, pa1, pa2, pa3, pa4, pa5, pa6, pa7;
    TTILE(0, pa0, pa1);
    TTILE(1, pa2, pa3);
    TTILE(2, pa4, pa5);
    TTILE(3, pa6, pa7);

    __syncthreads();  // V[kt] resident; all waves done reading Ks

    // prefetch K[kt+1] into Ks; it flies during the PV phase below
    if (kt < qt) {
      const unsigned short* Kp = Kbase + (size_t)(kt + 1) * 128 * DH;
#pragma unroll
      for (int p = 0; p < 4; ++p) {
        int idx = p * 256 + tid;
        int row = idx >> 3, ch = idx & 7;
        int sc = (ch ^ (row & 7)) << 3;
        gll16(Kp + row * 64 + sc, Ks + idx * 8);
      }
    }

    // O += P V : A = named pa regs, B = V from Vs
    PVSTEP(0, pa0); PVSTEP(1, pa1); PVSTEP(2, pa2); PVSTEP(3, pa3);
    PVSTEP(4, pa4); PVSTEP(5, pa5); PVSTEP(6, pa6); PVSTEP(7, pa7);

    __syncthreads();  // K[kt+1] resident; Vs WAR before next iteration's V issue
  }

  // epilogue: combine halves of l, per-row rcp, write ctx
  float l = (la0 + la1) + (la2 + la3);
  l += __shfl_xor(l, 32);  // lane l31=q now holds full denom for q
#pragma unroll
  for (int r = 0; r < 16; ++r) {
    int qrow = (r & 3) + 8 * (r >> 2) + 4 * half;
    float lr = __shfl(l, qrow);
    float inv = __builtin_amdgcn_rcpf(lr);
    int s = qt * 128 + wave * 32 + qrow;
    ctx[((size_t)(b * S_ + s)) * DM + h * DH + l31]      = f2bf(o0[r] * inv);
    ctx[((size_t)(b * S_ + s)) * DM + h * DH + 32 + l31] = f2bf(o1[r] * inv);
  }
}

// ---------------------------------------------------------------- launch
extern "C" void kernel_launch(void* const* d_in, const int* in_sizes, int n_in,
                              void* d_out, int out_size, void* d_ws, size_t ws_size,
                              hipStream_t stream) {
  (void)in_sizes; (void)n_in; (void)out_size; (void)ws_size;
  const float* x  = (const float*)d_in[0];
  const float* Wq = (const float*)d_in[1];
  const float* bq = (const float*)d_in[2];
  const float* Wk = (const float*)d_in[3];
  const float* bk = (const float*)d_in[4];
  const float* Wv = (const float*)d_in[5];
  const float* bv = (const float*)d_in[6];
  const float* Wo = (const float*)d_in[7];
  const float* bo = (const float*)d_in[8];
  float* out = (float*)d_out;

  char* ws = (char*)d_ws;
  size_t off = 0;
  auto carve = [&](size_t bytes) -> char* {
    char* p = ws + off;
    off += (bytes + 255) & ~(size_t)255;
    return p;
  };
  unsigned short* xb  = (unsigned short*)carve((size_t)MROWS * DM * 2);
  unsigned short* wtq = (unsigned short*)carve((size_t)3 * DM * DM * 2);
  unsigned short* wto = (unsigned short*)carve((size_t)DM * DM * 2);
  unsigned short* Qb  = (unsigned short*)carve((size_t)BH * S_ * DH * 2);
  unsigned short* Kb  = (unsigned short*)carve((size_t)BH * S_ * DH * 2);
  unsigned short* Vt  = (unsigned short*)carve((size_t)BH * S_ * DH * 2);
  unsigned short* ctx = (unsigned short*)carve((size_t)BH * S_ * DH * 2);

  prep_kernel<<<dim3(32, 32, 8), 256, 0, stream>>>(x, Wq, Wk, Wv, Wo, xb, wtq, wto);
  gemm_qkv_kernel<<<dim3(12, 32), 512, 0, stream>>>(xb, wtq, bq, bk, bv, Qb, Kb, Vt);
  attn_kernel<<<dim3(64, 16), 256, 0, stream>>>(Qb, Kb, Vt, ctx);
  gemm_out_kernel<<<dim3(8, 64), 256, 0, stream>>>(ctx, wto, bo, out);
}

// Round 8
// 249.626 us; speedup vs baseline: 1.0336x; 1.0336x over previous
//
#include <hip/hip_runtime.h>
#include <stdint.h>

#define B_    4
#define S_    2048
#define DM    1024
#define NH    16
#define DH    64
#define BH    (B_ * NH)    // 64
#define MROWS (B_ * S_)    // 8192
#define LOG2E 1.4426950408889634f

typedef __attribute__((ext_vector_type(8))) short short8;
typedef __attribute__((ext_vector_type(4))) float f32x4;
typedef __attribute__((ext_vector_type(16))) float f32x16;
typedef __attribute__((ext_vector_type(4))) unsigned int u32x4;

__device__ __forceinline__ unsigned short f2bf(float f) {
  unsigned int u = __float_as_uint(f);
  u = (u + 0x7FFFu + ((u >> 16) & 1u)) >> 16;
  return (unsigned short)u;
}
// round-half-up pack (PROVEN in R4)
__device__ __forceinline__ unsigned int pack_bf16(float lo, float hi) {
  unsigned int a = (__float_as_uint(lo) + 0x8000u) >> 16;
  unsigned int b = (__float_as_uint(hi) + 0x8000u) & 0xFFFF0000u;
  return a | b;
}

__device__ __forceinline__ void gll16(const void* g, const void* l) {
  __builtin_amdgcn_global_load_lds(
      (__attribute__((address_space(1))) void*)(unsigned long long)g,
      (__attribute__((address_space(3))) void*)(unsigned int)(unsigned long long)l,
      16, 0, 0);
}

// T1 chunked XCD swizzle (bijective: NWG % 8 == 0). HW assigns linear wgid
// round-robin to XCDs; remap so each XCD owns NWG/8 CONSECUTIVE swizzled ids
// = complete m-row groups -> per-XCD A slice is L2-resident instead of the
// whole A matrix being replicated in all 8 XCD L2s.
template <int NX, int NWG>
__device__ __forceinline__ void xcd_swz(int& bx, int& by) {
  int wgid = (int)blockIdx.x + NX * (int)blockIdx.y;
  int swz = (wgid & 7) * (NWG >> 3) + (wgid >> 3);
  bx = swz % NX;
  by = swz / NX;
}

// ---------------------------------------------------------------- prep
// z in [0,3]: W[z] fp32 [k][n] -> W^T bf16 [n][k].  z in [4,7]: x -> bf16.
__global__ __launch_bounds__(256) void prep_kernel(
    const float* __restrict__ x,
    const float* __restrict__ Wq, const float* __restrict__ Wk,
    const float* __restrict__ Wv, const float* __restrict__ Wo,
    unsigned short* __restrict__ xb,
    unsigned short* __restrict__ wt_qkv, unsigned short* __restrict__ wt_o) {
  __shared__ float t[32][33];
  const int z = blockIdx.z;
  if (z >= 4) {
    size_t lb = (size_t)(z - 4) * 1024 + blockIdx.y * 32 + blockIdx.x;
    size_t i = (lb * 256 + threadIdx.x) * 8;
    float4 a = *(const float4*)(x + i);
    float4 b = *(const float4*)(x + i + 4);
    short8 o;
    o[0] = (short)f2bf(a.x); o[1] = (short)f2bf(a.y);
    o[2] = (short)f2bf(a.z); o[3] = (short)f2bf(a.w);
    o[4] = (short)f2bf(b.x); o[5] = (short)f2bf(b.y);
    o[6] = (short)f2bf(b.z); o[7] = (short)f2bf(b.w);
    *(short8*)(xb + i) = o;
    return;
  }
  const float* W = z == 0 ? Wq : z == 1 ? Wk : z == 2 ? Wv : Wo;
  unsigned short* dst = z < 3 ? wt_qkv + (size_t)z * DM * DM : wt_o;
  const int nb = blockIdx.x * 32, kb = blockIdx.y * 32;
  const int tx = threadIdx.x & 31, ty = threadIdx.x >> 5;
#pragma unroll
  for (int p = 0; p < 4; ++p) {
    int r = ty + p * 8;
    t[r][tx] = W[(size_t)(kb + r) * DM + nb + tx];
  }
  __syncthreads();
#pragma unroll
  for (int p = 0; p < 4; ++p) {
    int r = ty + p * 8;
    dst[(size_t)(nb + r) * DM + kb + tx] = f2bf(t[tx][r]);
  }
}

// ---------------------------------------------------------------- GEMM core
// 32x32x16 MFMA; layouts HW-verified (m74/m101/m89). PROVEN 128x128 core.
// R7 note: 256^2 8-phase port REGRESSED here (97.5us vs 76.6us): grid was
// 384 blocks at 1 block/CU (1.5 dispatch waves -> 33% tail idle) and phases
// carried only 8 MFMA between raw barriers -> barrier-dominated. The m201
// template's regime (grid >> CUs, K >> 1024) is not this shape. Reverted.
__device__ __forceinline__ void gemm_core(const unsigned short* __restrict__ A,
                                          const unsigned short* __restrict__ Bt,
                                          int m0, int n0,
                                          unsigned short* As, unsigned short* Bs,
                                          f32x16 (&acc)[2][2]) {
  const int tid = threadIdx.x;
  const int lane = tid & 63, wave = tid >> 6;
  const int l31 = lane & 31, half = lane >> 5;
  const int wm = (wave >> 1) * 64, wn = (wave & 1) * 64;

  for (int kk = 0; kk < DM; kk += 64) {
#pragma unroll
    for (int p = 0; p < 4; ++p) {
      int idx = p * 256 + tid;
      int row = idx >> 3, ch = idx & 7;
      int sc = (ch ^ (row & 7)) << 3;
      gll16(A  + (size_t)(m0 + row) * DM + kk + sc, As + idx * 8);
      gll16(Bt + (size_t)(n0 + row) * DM + kk + sc, Bs + idx * 8);
    }
    __syncthreads();
#pragma unroll
    for (int ks = 0; ks < 4; ++ks) {   // 4 k-steps of 16
      short8 af[2], bf[2];
#pragma unroll
      for (int mi = 0; mi < 2; ++mi) {
        int row = wm + mi * 32 + l31;
        af[mi] = *(const short8*)&As[row * 64 + (((ks * 2 + half) ^ (l31 & 7)) << 3)];
      }
#pragma unroll
      for (int nj = 0; nj < 2; ++nj) {
        int row = wn + nj * 32 + l31;
        bf[nj] = *(const short8*)&Bs[row * 64 + (((ks * 2 + half) ^ (l31 & 7)) << 3)];
      }
#pragma unroll
      for (int mi = 0; mi < 2; ++mi)
#pragma unroll
        for (int nj = 0; nj < 2; ++nj)
          acc[mi][nj] = __builtin_amdgcn_mfma_f32_32x32x16_bf16(af[mi], bf[nj], acc[mi][nj], 0, 0, 0);
    }
    __syncthreads();
  }
}

// QKV projection (128^2 proven core + T1 XCD swizzle). V written directly
// in transposed [bh][d][s] layout.
__global__ __launch_bounds__(256) void gemm_qkv_kernel(
    const unsigned short* __restrict__ xb, const unsigned short* __restrict__ wt,
    const float* __restrict__ bq, const float* __restrict__ bk, const float* __restrict__ bv,
    unsigned short* __restrict__ Qb, unsigned short* __restrict__ Kb,
    unsigned short* __restrict__ Vt) {
  __shared__ unsigned short As[128 * 64];
  __shared__ unsigned short Bs[128 * 64];
  f32x16 acc[2][2] = {};
  int bx, by;
  xcd_swz<24, 24 * 64>(bx, by);   // each XCD: 8 full m-rows (2 MB A, L2-fit)
  const int m0 = by * 128, n0 = bx * 128;
  gemm_core(xb, wt, m0, n0, As, Bs, acc);

  const int tid = threadIdx.x, lane = tid & 63, wave = tid >> 6;
  const int l31 = lane & 31, half = lane >> 5;
  const int wm = (wave >> 1) * 64, wn = (wave & 1) * 64;
  const int which = n0 >> 10;
  const int nb = n0 - (which << 10);
  if (which == 2) {
    // V -> Vt[bh][d][s]
#pragma unroll
    for (int nj = 0; nj < 2; ++nj) {
      int n10 = nb + wn + nj * 32 + l31;
      float bsv = bv[n10];
      int h = n10 >> 6, d = n10 & 63;
#pragma unroll
      for (int mi = 0; mi < 2; ++mi) {
#pragma unroll
        for (int reg = 0; reg < 16; ++reg) {
          int m = m0 + wm + mi * 32 + (reg & 3) + 8 * (reg >> 2) + 4 * half;
          int b = m >> 11, s = m & 2047;
          Vt[(((size_t)(b * NH + h)) * DH + d) * S_ + s] = f2bf(acc[mi][nj][reg] + bsv);
        }
      }
    }
    return;
  }
  const float* bias = which == 0 ? bq : bk;
  unsigned short* dst = which == 0 ? Qb : Kb;
  const float scale = (which == 0) ? 0.125f * LOG2E : 1.0f;
#pragma unroll
  for (int nj = 0; nj < 2; ++nj) {
    int n10 = nb + wn + nj * 32 + l31;
    float bsv = bias[n10];
    int h = n10 >> 6, d = n10 & 63;
#pragma unroll
    for (int mi = 0; mi < 2; ++mi) {
#pragma unroll
      for (int reg = 0; reg < 16; ++reg) {
        int m = m0 + wm + mi * 32 + (reg & 3) + 8 * (reg >> 2) + 4 * half;
        int b = m >> 11, s = m & 2047;
        float v = (acc[mi][nj][reg] + bsv) * scale;
        dst[(((size_t)(b * NH + h)) * S_ + s) * DH + d] = f2bf(v);
      }
    }
  }
}

__global__ __launch_bounds__(256) void gemm_out_kernel(
    const unsigned short* __restrict__ ctx, const unsigned short* __restrict__ wto,
    const float* __restrict__ bo, float* __restrict__ out) {
  __shared__ unsigned short As[128 * 64];
  __shared__ unsigned short Bs[128 * 64];
  f32x16 acc[2][2] = {};
  int bx, by;
  xcd_swz<8, 8 * 64>(bx, by);     // each XCD: 8 full m-rows of ctx (L2-fit)
  const int m0 = by * 128, n0 = bx * 128;
  gemm_core(ctx, wto, m0, n0, As, Bs, acc);

  const int tid = threadIdx.x, lane = tid & 63, wave = tid >> 6;
  const int l31 = lane & 31, half = lane >> 5;
  const int wm = (wave >> 1) * 64, wn = (wave & 1) * 64;
#pragma unroll
  for (int nj = 0; nj < 2; ++nj) {
    int n = n0 + wn + nj * 32 + l31;
    float bsv = bo[n];
#pragma unroll
    for (int mi = 0; mi < 2; ++mi) {
#pragma unroll
      for (int reg = 0; reg < 16; ++reg) {
        int m = m0 + wm + mi * 32 + (reg & 3) + 8 * (reg >> 2) + 4 * half;
        out[(size_t)m * DM + n] = acc[mi][nj][reg] + bsv;
      }
    }
  }
}

// ---------------------------------------------------------------- attention
// R6 PASSING version (32x32x16, shfl_xor+select transform, named regs,
// launch_bounds (256,2)). UNCHANGED. Default blockIdx mapping already puts
// all 16 q-tiles of a bh on one XCD (64%8==0) — no swizzle needed.

#define TTILE(T, PAE, PAO) do {                                              \
    f32x16 sa;                                                               \
    _Pragma("unroll") for (int r = 0; r < 16; ++r) sa[r] = -8.f;             \
    {                                                                        \
      int row = (T) * 32 + l31;                                              \
      _Pragma("unroll") for (int ks = 0; ks < 4; ++ks) {                     \
        short8 kf = *(const short8*)&Ks[row * 64 +                           \
                      (((ks * 2 + half) ^ (row & 7)) << 3)];                 \
        sa = __builtin_amdgcn_mfma_f32_32x32x16_bf16(kf, qf[ks], sa, 0, 0, 0);\
      }                                                                      \
    }                                                                        \
    if (kt == qt) {                                                          \
      int ql = wave * 32 + l31;                                              \
      _Pragma("unroll") for (int r = 0; r < 16; ++r) {                       \
        int kv = (T) * 32 + (r & 3) + 8 * (r >> 2) + 4 * half;               \
        if (kv > ql) sa[r] = -__builtin_inff();                              \
      }                                                                      \
    }                                                                        \
    float p[16];                                                             \
    _Pragma("unroll") for (int r = 0; r < 16; ++r)                           \
      p[r] = __builtin_amdgcn_exp2f(sa[r]);                                  \
    la0 += p[0] + p[4] + p[8]  + p[12];                                      \
    la1 += p[1] + p[5] + p[9]  + p[13];                                      \
    la2 += p[2] + p[6] + p[10] + p[14];                                      \
    la3 += p[3] + p[7] + p[11] + p[15];                                      \
    {                                                                        \
      unsigned int A0 = pack_bf16(p[0], p[1]), A1 = pack_bf16(p[2], p[3]);   \
      unsigned int B0 = pack_bf16(p[4], p[5]), B1 = pack_bf16(p[6], p[7]);   \
      unsigned int A0x = (unsigned int)__shfl_xor((int)A0, 32);              \
      unsigned int A1x = (unsigned int)__shfl_xor((int)A1, 32);              \
      unsigned int B0x = (unsigned int)__shfl_xor((int)B0, 32);              \
      unsigned int B1x = (unsigned int)__shfl_xor((int)B1, 32);              \
      u32x4 fa;                                                              \
      fa[0] = half ? B0x : A0;                                               \
      fa[1] = half ? B1x : A1;                                               \
      fa[2] = half ? B0  : A0x;                                              \
      fa[3] = half ? B1  : A1x;                                              \
      PAE = __builtin_bit_cast(short8, fa);                                  \
    }                                                                        \
    {                                                                        \
      unsigned int C0 = pack_bf16(p[8], p[9]),   C1 = pack_bf16(p[10], p[11]);\
      unsigned int D0 = pack_bf16(p[12], p[13]), D1 = pack_bf16(p[14], p[15]);\
      unsigned int C0x = (unsigned int)__shfl_xor((int)C0, 32);              \
      unsigned int C1x = (unsigned int)__shfl_xor((int)C1, 32);              \
      unsigned int D0x = (unsigned int)__shfl_xor((int)D0, 32);              \
      unsigned int D1x = (unsigned int)__shfl_xor((int)D1, 32);              \
      u32x4 fb;                                                              \
      fb[0] = half ? D0x : C0;                                               \
      fb[1] = half ? D1x : C1;                                               \
      fb[2] = half ? D0  : C0x;                                              \
      fb[3] = half ? D1  : C1x;                                              \
      PAO = __builtin_bit_cast(short8, fb);                                  \
    }                                                                        \
  } while (0)

#define PVSTEP(S2, PA) do {                                                  \
    int c = (S2) * 2 + half;                                                 \
    {                                                                        \
      int row = l31;                                                         \
      short8 vf = *(const short8*)&Vs[row * 128 +                            \
                    (((c & 8) | ((c ^ row) & 7)) << 3)];                     \
      o0 = __builtin_amdgcn_mfma_f32_32x32x16_bf16(PA, vf, o0, 0, 0, 0);     \
    }                                                                        \
    {                                                                        \
      int row = 32 + l31;                                                    \
      short8 vf = *(const short8*)&Vs[row * 128 +                            \
                    (((c & 8) | ((c ^ row) & 7)) << 3)];                     \
      o1 = __builtin_amdgcn_mfma_f32_32x32x16_bf16(PA, vf, o1, 0, 0, 0);     \
    }                                                                        \
  } while (0)

__global__ __launch_bounds__(256, 2) void attn_kernel(
    const unsigned short* __restrict__ Qb, const unsigned short* __restrict__ Kb,
    const unsigned short* __restrict__ Vt, unsigned short* __restrict__ ctx) {
  __shared__ unsigned short Ks[128 * 64];  // 16 KiB
  __shared__ unsigned short Vs[64 * 128];  // 16 KiB

  const int tid = threadIdx.x, lane = tid & 63, wave = tid >> 6;
  const int l31 = lane & 31, half = lane >> 5;
  const int bh = blockIdx.x;
  const int qt = 15 - blockIdx.y;
  const int b = bh >> 4, h = bh & 15;

  const unsigned short* Qp = Qb + ((size_t)bh * S_ + qt * 128) * DH;
  const unsigned short* Kbase = Kb + (size_t)bh * S_ * DH;
  const unsigned short* Vbase = Vt + (size_t)bh * DH * S_;

  // prologue: K tile 0 -> Ks (async); Q fragments -> registers (direct)
#pragma unroll
  for (int p = 0; p < 4; ++p) {
    int idx = p * 256 + tid;
    int row = idx >> 3, ch = idx & 7;
    int sc = (ch ^ (row & 7)) << 3;
    gll16(Kbase + row * 64 + sc, Ks + idx * 8);
  }
  // Q as B-operand: col=q=wave*32+l31, k=d=ks*16+half*8+j
  short8 qf[4];
#pragma unroll
  for (int ks = 0; ks < 4; ++ks)
    qf[ks] = *(const short8*)(Qp + (wave * 32 + l31) * 64 + ks * 16 + half * 8);
  __syncthreads();  // Ks[0] resident

  f32x16 o0 = {}, o1 = {};  // O: col=d=jd*32+l31, row=q=(r&3)+8*(r>>2)+4*half
  float la0 = 0.f, la1 = 0.f, la2 = 0.f, la3 = 0.f;

  for (int kt = 0; kt <= qt; ++kt) {
    // issue V[kt] NOW; it flies during S + softmax
    const unsigned short* Vp = Vbase + kt * 128;
#pragma unroll
    for (int p = 0; p < 4; ++p) {
      int idx = p * 256 + tid;
      int row = idx >> 4, ch = idx & 15;
      int sc = (ch & 8) | ((ch ^ row) & 7);
      gll16(Vp + (size_t)row * S_ + sc * 8, Vs + idx * 8);
    }

    // S^T = K * Q^T - 8, softmax + pack + cross-half exchange, all in-register
    short8 pa0, pa1, pa2, pa3, pa4, pa5, pa6, pa7;
    TTILE(0, pa0, pa1);
    TTILE(1, pa2, pa3);
    TTILE(2, pa4, pa5);
    TTILE(3, pa6, pa7);

    __syncthreads();  // V[kt] resident; all waves done reading Ks

    // prefetch K[kt+1] into Ks; it flies during the PV phase below
    if (kt < qt) {
      const unsigned short* Kp = Kbase + (size_t)(kt + 1) * 128 * DH;
#pragma unroll
      for (int p = 0; p < 4; ++p) {
        int idx = p * 256 + tid;
        int row = idx >> 3, ch = idx & 7;
        int sc = (ch ^ (row & 7)) << 3;
        gll16(Kp + row * 64 + sc, Ks + idx * 8);
      }
    }

    // O += P V : A = named pa regs, B = V from Vs
    PVSTEP(0, pa0); PVSTEP(1, pa1); PVSTEP(2, pa2); PVSTEP(3, pa3);
    PVSTEP(4, pa4); PVSTEP(5, pa5); PVSTEP(6, pa6); PVSTEP(7, pa7);

    __syncthreads();  // K[kt+1] resident; Vs WAR before next iteration's V issue
  }

  // epilogue: combine halves of l, per-row rcp, write ctx
  float l = (la0 + la1) + (la2 + la3);
  l += __shfl_xor(l, 32);  // lane l31=q now holds full denom for q
#pragma unroll
  for (int r = 0; r < 16; ++r) {
    int qrow = (r & 3) + 8 * (r >> 2) + 4 * half;
    float lr = __shfl(l, qrow);
    float inv = __builtin_amdgcn_rcpf(lr);
    int s = qt * 128 + wave * 32 + qrow;
    ctx[((size_t)(b * S_ + s)) * DM + h * DH + l31]      = f2bf(o0[r] * inv);
    ctx[((size_t)(b * S_ + s)) * DM + h * DH + 32 + l31] = f2bf(o1[r] * inv);
  }
}

// ---------------------------------------------------------------- launch
extern "C" void kernel_launch(void* const* d_in, const int* in_sizes, int n_in,
                              void* d_out, int out_size, void* d_ws, size_t ws_size,
                              hipStream_t stream) {
  (void)in_sizes; (void)n_in; (void)out_size; (void)ws_size;
  const float* x  = (const float*)d_in[0];
  const float* Wq = (const float*)d_in[1];
  const float* bq = (const float*)d_in[2];
  const float* Wk = (const float*)d_in[3];
  const float* bk = (const float*)d_in[4];
  const float* Wv = (const float*)d_in[5];
  const float* bv = (const float*)d_in[6];
  const float* Wo = (const float*)d_in[7];
  const float* bo = (const float*)d_in[8];
  float* out = (float*)d_out;

  char* ws = (char*)d_ws;
  size_t off = 0;
  auto carve = [&](size_t bytes) -> char* {
    char* p = ws + off;
    off += (bytes + 255) & ~(size_t)255;
    return p;
  };
  unsigned short* xb  = (unsigned short*)carve((size_t)MROWS * DM * 2);
  unsigned short* wtq = (unsigned short*)carve((size_t)3 * DM * DM * 2);
  unsigned short* wto = (unsigned short*)carve((size_t)DM * DM * 2);
  unsigned short* Qb  = (unsigned short*)carve((size_t)BH * S_ * DH * 2);
  unsigned short* Kb  = (unsigned short*)carve((size_t)BH * S_ * DH * 2);
  unsigned short* Vt  = (unsigned short*)carve((size_t)BH * S_ * DH * 2);
  unsigned short* ctx = (unsigned short*)carve((size_t)BH * S_ * DH * 2);

  prep_kernel<<<dim3(32, 32, 8), 256, 0, stream>>>(x, Wq, Wk, Wv, Wo, xb, wtq, wto);
  gemm_qkv_kernel<<<dim3(24, 64), 256, 0, stream>>>(xb, wtq, bq, bk, bv, Qb, Kb, Vt);
  attn_kernel<<<dim3(64, 16), 256, 0, stream>>>(Qb, Kb, Vt, ctx);
  gemm_out_kernel<<<dim3(8, 64), 256, 0, stream>>>(ctx, wto, bo, out);
}